// Round 2
// baseline (175.331 us; speedup 1.0000x reference)
//
#include <hip/hip_runtime.h>
#include <hip/hip_bf16.h>

typedef __bf16 bf16x8 __attribute__((ext_vector_type(8)));
typedef float  f32x4  __attribute__((ext_vector_type(4)));

namespace {
constexpr int NB = 4, CINc = 256, Hc = 56, Wc = 56, COUTc = 256;
constexpr int LSP = 56 * 56;           // 3136 output pixels per image
constexpr int MD  = NB * LSP;          // 12544 GEMM rows
constexpr int KT  = 2304;              // 256*9
constexpr int YP = 58, XP = 58;        // padded spatial

constexpr size_t OFF_A0 = 256;
constexpr size_t SZ_ACL = (size_t)NB * YP * XP * 256 * 2;   // 6,889,472
constexpr size_t OFF_A1 = OFF_A0 + SZ_ACL;
constexpr size_t OFF_BW = OFF_A1 + SZ_ACL;
constexpr size_t SZ_BW  = (size_t)COUTc * KT * 2;           // 1,179,648
constexpr size_t OFF_P0 = OFF_BW + SZ_BW;
constexpr size_t SZ_P   = (size_t)MD * COUTc * 2;           // 6,422,528
constexpr size_t OFF_P1 = OFF_P0 + SZ_P;                    // total ~27.8 MB
} // namespace

__global__ __launch_bounds__(256) void k_absmax(const float* __restrict__ x,
                                                unsigned int* scal, int n4) {
  float mx = 0.f;
  const float4* x4 = (const float4*)x;
  for (int i = blockIdx.x * blockDim.x + threadIdx.x; i < n4; i += gridDim.x * blockDim.x) {
    float4 v = x4[i];
    mx = fmaxf(mx, fmaxf(fmaxf(fabsf(v.x), fabsf(v.y)), fmaxf(fabsf(v.z), fabsf(v.w))));
  }
#pragma unroll
  for (int off = 32; off; off >>= 1) mx = fmaxf(mx, __shfl_xor(mx, off));
  __shared__ float red[4];
  if ((threadIdx.x & 63) == 0) red[threadIdx.x >> 6] = mx;
  __syncthreads();
  if (threadIdx.x == 0) {
    mx = fmaxf(fmaxf(red[0], red[1]), fmaxf(red[2], red[3]));
    atomicMax(scal, __float_as_uint(mx));
  }
}

// 1024 threads: phase1 quantize (c = tid&255, w-quarter = tid>>8), phase2 coalesced int4 stores
__global__ __launch_bounds__(1024) void k_quant(const float* __restrict__ x,
                                                const unsigned int* __restrict__ scal,
                                                unsigned short* __restrict__ a0,
                                                unsigned short* __restrict__ a1) {
  __shared__ unsigned short t0[56 * 256];
  __shared__ unsigned short t1[56 * 256];
  const int n = blockIdx.x / Hc, h = blockIdx.x % Hc;
  const float sx = fmaxf(__fdiv_rn(__uint_as_float(scal[0]), 7.0f), 1e-12f);
  const int c = threadIdx.x & 255, wq = threadIdx.x >> 8;
  const float2* src = (const float2*)(x + (((size_t)n * CINc + c) * Hc + h) * Wc + wq * 14);
#pragma unroll
  for (int j = 0; j < 7; ++j) {
    float2 v = src[j];
    float arr[2] = {v.x, v.y};
#pragma unroll
    for (int e = 0; e < 2; ++e) {
      float qf = rintf(__fdiv_rn(arr[e], sx));
      qf = fminf(7.f, fmaxf(-7.f, qf));
      int qi = (int)qf;
      int mag = qi < 0 ? -qi : qi;
      int s0 = mag & 3, s1 = mag >> 2;
      if (qi < 0) { s0 = -s0; s1 = -s1; }
      int w = wq * 14 + j * 2 + e;
      t0[w * 256 + c] = (unsigned short)(__float_as_uint((float)s0) >> 16);
      t1[w * 256 + c] = (unsigned short)(__float_as_uint((float)s1) >> 16);
    }
  }
  __syncthreads();
#pragma unroll
  for (int p = 0; p < 2; ++p) {
    int idx = p * 1024 + threadIdx.x;          // 56*32 = 1792 int4 slots per array
    if (idx < 1792) {
      int wr = idx >> 5, c8 = (idx & 31) << 3;
      int4 v0 = *(const int4*)&t0[wr * 256 + c8];
      int4 v1 = *(const int4*)&t1[wr * 256 + c8];
      size_t dst = (((size_t)n * YP + (h + 1)) * XP + (wr + 1)) * 256 + c8;
      *(int4*)&a0[dst] = v0;
      *(int4*)&a1[dst] = v1;
    }
  }
}

// one block per co: coalesced reads (wave spans 2304B contiguous) + coalesced u16 writes
__global__ __launch_bounds__(256) void k_binw(const float* __restrict__ w,
                                              unsigned short* __restrict__ bw) {
  const int co = blockIdx.x, cin = threadIdx.x;
  const float* src = w + (size_t)co * KT + cin * 9;
  unsigned short* dst = bw + (size_t)co * KT + cin;
#pragma unroll
  for (int s = 0; s < 9; ++s) {
    float v = src[s];
    dst[s * 256] = v >= 0.f ? 0x3F80u : 0xBF80u;
  }
}

// 64x64 tile, 4 waves of 32x32, dual accumulator (p0,p1). 784 blocks -> ~3 blocks/CU.
__global__ __launch_bounds__(256) void k_gemm(const unsigned short* __restrict__ a0cl,
                                              const unsigned short* __restrict__ a1cl,
                                              const unsigned short* __restrict__ bw,
                                              short* __restrict__ p0, short* __restrict__ p1,
                                              int* scal) {
  __shared__ __align__(16) char sA0[64 * 128];
  __shared__ __align__(16) char sA1[64 * 128];
  __shared__ __align__(16) char sB[64 * 128];
  __shared__ float red[8];

  const int tid = threadIdx.x;
  const int lane = tid & 63, wid = tid >> 6;
  const int wm = wid >> 1, wn = wid & 1;          // 2x2 waves, 32x32 each

  // bijective XCD swizzle: 784 = 8*98; m-fastest so same-XCD blocks share the B panel
  const int bid = blockIdx.x;
  const int wg = (bid & 7) * 98 + (bid >> 3);
  const int mblk = wg % (MD / 64), nblk = wg / (MD / 64);
  const int m0 = mblk * 64, n0 = nblk * 64;

  f32x4 acc0[2][2] = {};
  f32x4 acc1[2][2] = {};

  const int trow = tid >> 2;          // 0..63: one staged row per thread
  const int tseg = (tid & 3) * 16;    // two 16B segments: tseg, tseg+64

  int rn, roh, row_;
  {
    int m = m0 + trow;
    rn = m / LSP; int l = m - rn * LSP;
    roh = l / 56; row_ = l - roh * 56;
  }
  const int swz = (trow & 7) << 4;
  const int dst0 = trow * 128 + (tseg ^ swz);
  const int dst1 = trow * 128 + ((tseg + 64) ^ swz);

#pragma unroll 1
  for (int kb = 0; kb < KT / 64; ++kb) {
    const int slab = kb >> 2;
    const int kh = slab / 3, kw = slab - (slab / 3) * 3;
    const int c0 = (kb & 3) << 6;
    __syncthreads();
    {
      size_t ga = ((((size_t)rn * YP + (roh + kh)) * XP + (row_ + kw)) << 8) + c0;
      const char* pa0 = (const char*)a0cl + ga * 2;
      const char* pa1 = (const char*)a1cl + ga * 2;
      size_t gb = ((size_t)(n0 + trow) * KT + kb * 64) * 2;
      const char* pb = (const char*)bw + gb;
      *(int4*)(sA0 + dst0) = *(const int4*)(pa0 + tseg);
      *(int4*)(sA0 + dst1) = *(const int4*)(pa0 + tseg + 64);
      *(int4*)(sA1 + dst0) = *(const int4*)(pa1 + tseg);
      *(int4*)(sA1 + dst1) = *(const int4*)(pa1 + tseg + 64);
      *(int4*)(sB + dst0) = *(const int4*)(pb + tseg);
      *(int4*)(sB + dst1) = *(const int4*)(pb + tseg + 64);
    }
    __syncthreads();
#pragma unroll
    for (int ks = 0; ks < 2; ++ks) {
      const int kbyte = ks * 64 + ((lane >> 4) << 4);
      bf16x8 bfr[2], a0f[2], a1f[2];
#pragma unroll
      for (int r = 0; r < 2; ++r) {
        int rr = wn * 32 + r * 16 + (lane & 15);
        bfr[r] = *(const bf16x8*)(sB + rr * 128 + (kbyte ^ ((rr & 7) << 4)));
      }
#pragma unroll
      for (int q = 0; q < 2; ++q) {
        int rr = wm * 32 + q * 16 + (lane & 15);
        int off = rr * 128 + (kbyte ^ ((rr & 7) << 4));
        a0f[q] = *(const bf16x8*)(sA0 + off);
        a1f[q] = *(const bf16x8*)(sA1 + off);
      }
#pragma unroll
      for (int q = 0; q < 2; ++q)
#pragma unroll
        for (int r = 0; r < 2; ++r) {
          acc0[q][r] = __builtin_amdgcn_mfma_f32_16x16x32_bf16(a0f[q], bfr[r], acc0[q][r], 0, 0, 0);
          acc1[q][r] = __builtin_amdgcn_mfma_f32_16x16x32_bf16(a1f[q], bfr[r], acc1[q][r], 0, 0, 0);
        }
    }
  }

  float mx0 = 0.f, mx1 = 0.f;
#pragma unroll
  for (int q = 0; q < 2; ++q)
#pragma unroll
    for (int r = 0; r < 2; ++r) {
      const int mrow0 = m0 + wm * 32 + q * 16 + ((lane >> 4) << 2);
      const int co = n0 + wn * 32 + r * 16 + (lane & 15);
#pragma unroll
      for (int e = 0; e < 4; ++e) {
        float v0 = acc0[q][r][e], v1 = acc1[q][r][e];
        mx0 = fmaxf(mx0, fabsf(v0));
        mx1 = fmaxf(mx1, fabsf(v1));
        size_t idx = (size_t)(mrow0 + e) * COUTc + co;
        p0[idx] = (short)v0;
        p1[idx] = (short)v1;
      }
    }
#pragma unroll
  for (int off = 32; off; off >>= 1) {
    mx0 = fmaxf(mx0, __shfl_xor(mx0, off));
    mx1 = fmaxf(mx1, __shfl_xor(mx1, off));
  }
  if (lane == 0) { red[wid] = mx0; red[wid + 4] = mx1; }
  __syncthreads();
  if (tid == 0) {
    float a = fmaxf(fmaxf(red[0], red[1]), fmaxf(red[2], red[3]));
    float b = fmaxf(fmaxf(red[4], red[5]), fmaxf(red[6], red[7]));
    atomicMax(scal + 1, (int)a);
    atomicMax(scal + 2, (int)b);
  }
}

__device__ __forceinline__ float compute_val(int a, int b, float sa0, float sa1) {
  float q0 = rintf(__fdiv_rn((float)a, sa0));
  q0 = fminf(31.f, fmaxf(-31.f, q0));
  float q1 = rintf(__fdiv_rn((float)b, sa1));
  q1 = fminf(31.f, fmaxf(-31.f, q1));
  float acc = __fadd_rn(__fmul_rn(q0, sa0), __fmul_rn(__fmul_rn(q1, sa1), 4.0f));
  float pe = (float)(a + 4 * b);
  return __fadd_rn(pe, __fsub_rn(acc, pe));
}

__global__ __launch_bounds__(256) void k_maxval(const short* __restrict__ p0,
                                                const short* __restrict__ p1,
                                                const int* __restrict__ scal,
                                                unsigned int* scalu) {
  const float sa0 = fmaxf(__fdiv_rn((float)scal[1], 31.0f), 1e-12f);
  const float sa1 = fmaxf(__fdiv_rn((float)scal[2], 31.0f), 1e-12f);
  int i = blockIdx.x * 256 + threadIdx.x;
  const short4 a = ((const short4*)p0)[i];
  const short4 b = ((const short4*)p1)[i];
  float mx = fmaxf(fmaxf(fabsf(compute_val(a.x, b.x, sa0, sa1)),
                         fabsf(compute_val(a.y, b.y, sa0, sa1))),
                   fmaxf(fabsf(compute_val(a.z, b.z, sa0, sa1)),
                         fabsf(compute_val(a.w, b.w, sa0, sa1))));
#pragma unroll
  for (int off = 32; off; off >>= 1) mx = fmaxf(mx, __shfl_xor(mx, off));
  __shared__ float red[4];
  if ((threadIdx.x & 63) == 0) red[threadIdx.x >> 6] = mx;
  __syncthreads();
  if (threadIdx.x == 0) {
    mx = fmaxf(fmaxf(red[0], red[1]), fmaxf(red[2], red[3]));
    atomicMax(scalu + 3, __float_as_uint(mx));
  }
}

__global__ __launch_bounds__(256) void k_final(const short* __restrict__ p0,
                                               const short* __restrict__ p1,
                                               const unsigned int* __restrict__ scalu,
                                               const float* __restrict__ bias,
                                               float* __restrict__ out) {
  __shared__ short t0[64 * 66];
  __shared__ short t1[64 * 66];
  const int* scali = (const int*)scalu;
  const float sx  = fmaxf(__fdiv_rn(__uint_as_float(scalu[0]), 7.0f), 1e-12f);
  const float sa0 = fmaxf(__fdiv_rn((float)scali[1], 31.0f), 1e-12f);
  const float sa1 = fmaxf(__fdiv_rn((float)scali[2], 31.0f), 1e-12f);
  const float so  = fmaxf(__fdiv_rn(__fmul_rn(__uint_as_float(scalu[3]), sx), 127.0f), 1e-12f);

  const int m0 = blockIdx.x * 64, co0 = blockIdx.y * 64;
  const int trow = threadIdx.x >> 3, tseg = threadIdx.x & 7;
#pragma unroll
  for (int p = 0; p < 2; ++p) {
    int ml = p * 32 + trow;
    int4 v0 = *(const int4*)&p0[(size_t)(m0 + ml) * COUTc + co0 + tseg * 8];
    int4 v1 = *(const int4*)&p1[(size_t)(m0 + ml) * COUTc + co0 + tseg * 8];
    const short* s0 = (const short*)&v0;
    const short* s1 = (const short*)&v1;
#pragma unroll
    for (int j = 0; j < 8; ++j) {
      int col = tseg * 8 + j;
      t0[col * 66 + ml] = s0[j];
      t1[col * 66 + ml] = s1[j];
    }
  }
  __syncthreads();
  const int lane16 = threadIdx.x & 15, cg = threadIdx.x >> 4;
#pragma unroll
  for (int p = 0; p < 4; ++p) {
    int col = p * 16 + cg;
    int m4 = lane16 * 4;
    int mg = m0 + m4;
    int nimg = mg / LSP;
    int l = mg - nimg * LSP;
    int co = co0 + col;
    float bv = bias[co];
    float4 o;
    float* op = &o.x;
#pragma unroll
    for (int e = 0; e < 4; ++e) {
      float val = compute_val(t0[col * 66 + m4 + e], t1[col * 66 + m4 + e], sa0, sa1);
      float u = __fmul_rn(val, sx);
      float r = rintf(__fdiv_rn(u, so));
      r = fminf(127.f, fmaxf(-127.f, r));
      op[e] = __fadd_rn(__fmul_rn(r, so), bv);
    }
    *(float4*)&out[((size_t)nimg * COUTc + co) * LSP + l] = o;
  }
}

extern "C" void kernel_launch(void* const* d_in, const int* in_sizes, int n_in,
                              void* d_out, int out_size, void* d_ws, size_t ws_size,
                              hipStream_t stream) {
  const float* x    = (const float*)d_in[0];
  const float* w    = (const float*)d_in[1];
  const float* bias = (const float*)d_in[2];
  float* out = (float*)d_out;
  char* ws = (char*)d_ws;

  unsigned int* scalu = (unsigned int*)ws;
  int* scali = (int*)ws;
  unsigned short* a0 = (unsigned short*)(ws + OFF_A0);
  unsigned short* a1 = (unsigned short*)(ws + OFF_A1);
  unsigned short* bw = (unsigned short*)(ws + OFF_BW);
  short* p0 = (short*)(ws + OFF_P0);
  short* p1 = (short*)(ws + OFF_P1);

  hipMemsetAsync(ws, 0, 64, stream);
  hipMemsetAsync(ws + OFF_A0, 0, 2 * SZ_ACL, stream);

  k_absmax<<<1024, 256, 0, stream>>>(x, scalu, NB * CINc * Hc * Wc / 4);
  k_binw<<<COUTc, 256, 0, stream>>>(w, bw);
  k_quant<<<NB * Hc, 1024, 0, stream>>>(x, scalu, a0, a1);
  k_gemm<<<(MD / 64) * (COUTc / 64), 256, 0, stream>>>(a0, a1, bw, p0, p1, scali);
  k_maxval<<<(MD * COUTc) / (4 * 256), 256, 0, stream>>>(p0, p1, scali, scalu);
  k_final<<<dim3(MD / 64, COUTc / 64), 256, 0, stream>>>(p0, p1, scalu, bias, out);
}

// Round 3
// 119.110 us; speedup vs baseline: 1.4720x; 1.4720x over previous
//
#include <hip/hip_runtime.h>
#include <hip/hip_bf16.h>

typedef int i32x4 __attribute__((ext_vector_type(4)));

namespace {
constexpr int NB = 4, CINc = 256, Hc = 56, Wc = 56, COUTc = 256;
constexpr int LSP = 56 * 56;           // 3136 output pixels per image
constexpr int MD  = NB * LSP;          // 12544 GEMM rows
constexpr int KT  = 2304;              // 256*9
constexpr int YP = 58, XP = 58;        // padded spatial

// workspace (i8 activations/weights now)
constexpr size_t OFF_A0 = 256;
constexpr size_t SZ_ACL = (size_t)NB * YP * XP * 256;       // 3,444,736 (i8)
constexpr size_t OFF_A1 = OFF_A0 + SZ_ACL;
constexpr size_t OFF_BW = OFF_A1 + SZ_ACL;
constexpr size_t SZ_BW  = (size_t)COUTc * KT;               // 589,824 (i8)
constexpr size_t OFF_P0 = OFF_BW + SZ_BW;
constexpr size_t SZ_P   = (size_t)MD * COUTc * 2;           // 6,422,528 (i16)
constexpr size_t OFF_P1 = OFF_P0 + SZ_P;                    // total ~20.3 MB
} // namespace

__global__ __launch_bounds__(256) void k_absmax(const float* __restrict__ x,
                                                unsigned int* scal, int n4) {
  float mx = 0.f;
  const float4* x4 = (const float4*)x;
  for (int i = blockIdx.x * blockDim.x + threadIdx.x; i < n4; i += gridDim.x * blockDim.x) {
    float4 v = x4[i];
    mx = fmaxf(mx, fmaxf(fmaxf(fabsf(v.x), fabsf(v.y)), fmaxf(fabsf(v.z), fabsf(v.w))));
  }
#pragma unroll
  for (int off = 32; off; off >>= 1) mx = fmaxf(mx, __shfl_xor(mx, off));
  __shared__ float red[4];
  if ((threadIdx.x & 63) == 0) red[threadIdx.x >> 6] = mx;
  __syncthreads();
  if (threadIdx.x == 0) {
    mx = fmaxf(fmaxf(red[0], red[1]), fmaxf(red[2], red[3]));
    atomicMax(scal, __float_as_uint(mx));
  }
}

// quantize x -> i8 DAC slices, NCHW -> padded channels-last [n][y][x][c]
__global__ __launch_bounds__(1024) void k_quant(const float* __restrict__ x,
                                                const unsigned int* __restrict__ scal,
                                                char* __restrict__ a0,
                                                char* __restrict__ a1) {
  __shared__ char t0[56 * 256];
  __shared__ char t1[56 * 256];
  const int n = blockIdx.x / Hc, h = blockIdx.x % Hc;
  const float sx = fmaxf(__fdiv_rn(__uint_as_float(scal[0]), 7.0f), 1e-12f);
  const int c = threadIdx.x & 255, wq = threadIdx.x >> 8;
  const float2* src = (const float2*)(x + (((size_t)n * CINc + c) * Hc + h) * Wc + wq * 14);
#pragma unroll
  for (int j = 0; j < 7; ++j) {
    float2 v = src[j];
    float arr[2] = {v.x, v.y};
#pragma unroll
    for (int e = 0; e < 2; ++e) {
      float qf = rintf(__fdiv_rn(arr[e], sx));
      qf = fminf(7.f, fmaxf(-7.f, qf));
      int qi = (int)qf;
      int mag = qi < 0 ? -qi : qi;
      int s0 = mag & 3, s1 = mag >> 2;
      if (qi < 0) { s0 = -s0; s1 = -s1; }
      int w = wq * 14 + j * 2 + e;
      t0[w * 256 + c] = (char)s0;
      t1[w * 256 + c] = (char)s1;
    }
  }
  __syncthreads();
  {
    int idx = threadIdx.x;              // 56*16 = 896 int4 slots per array
    if (idx < 896) {
      int wr = idx >> 4, c16 = (idx & 15) << 4;
      int4 v0 = *(const int4*)&t0[wr * 256 + c16];
      int4 v1 = *(const int4*)&t1[wr * 256 + c16];
      size_t dst = (((size_t)n * YP + (h + 1)) * XP + (wr + 1)) * 256 + c16;
      *(int4*)&a0[dst] = v0;
      *(int4*)&a1[dst] = v1;
    }
  }
}

// binarize weights -> i8 {+1,-1}, reorder to [co][k'], k' = (kh*3+kw)*256 + cin
__global__ __launch_bounds__(256) void k_binw(const float* __restrict__ w,
                                              char* __restrict__ bw) {
  const int co = blockIdx.x, cin = threadIdx.x;
  const float* src = w + (size_t)co * KT + cin * 9;
  char* dst = bw + (size_t)co * KT + cin;
#pragma unroll
  for (int s = 0; s < 9; ++s) {
    float v = src[s];
    dst[s * 256] = v >= 0.f ? (char)1 : (char)-1;
  }
}

// 128x128 tile, 8 waves (4m x 2n, each 32x64), i8 MFMA, dual accumulator.
// 196 blocks of 512 threads -> 8 waves/CU on 196 CUs.
__global__ __launch_bounds__(512) void k_gemm(const char* __restrict__ a0cl,
                                              const char* __restrict__ a1cl,
                                              const char* __restrict__ bw,
                                              short* __restrict__ p0, short* __restrict__ p1,
                                              int* scal) {
  __shared__ __align__(16) char sA0[128 * 128];
  __shared__ __align__(16) char sA1[128 * 128];
  __shared__ __align__(16) char sB[128 * 128];
  __shared__ int red[16];

  const int tid = threadIdx.x;
  const int lane = tid & 63, wid = tid >> 6;
  const int wm = wid >> 1, wn = wid & 1;          // 4x2 waves, 32x64 each

  // bijective XCD swizzle for 196 blocks (196 = 8*24 + 4), n-fastest within chunk
  const int bid = blockIdx.x;
  const int xcd = bid & 7;
  const int wg = (xcd < 4 ? xcd * 25 : 100 + (xcd - 4) * 24) + (bid >> 3);
  const int nblk = wg & 1, mblk = wg >> 1;
  const int m0 = mblk * 128, n0 = nblk * 128;

  i32x4 acc0[2][4] = {};
  i32x4 acc1[2][4] = {};

  const int trow = tid >> 3;          // 0..63
  const int cb = (tid & 7) * 16;      // 16B seg within 128B row

  int rn[2], roh[2], rww[2];
#pragma unroll
  for (int p = 0; p < 2; ++p) {
    int m = m0 + p * 64 + trow;
    rn[p] = m / LSP; int l = m - rn[p] * LSP;
    roh[p] = l / 56; rww[p] = l - roh[p] * 56;
  }

#pragma unroll 1
  for (int kb = 0; kb < KT / 128; ++kb) {         // 18 iters, K-step = 128 i8
    const int slab = kb >> 1;                     // (kh,kw) 0..8
    const int kh = slab / 3, kw = slab - (slab / 3) * 3;
    const int c0 = (kb & 1) << 7;
    __syncthreads();
#pragma unroll
    for (int p = 0; p < 2; ++p) {
      const int r = p * 64 + trow;
      const int dst = r * 128 + (cb ^ ((r & 7) << 4));
      size_t ga = (((size_t)rn[p] * YP + (roh[p] + kh)) * XP + (rww[p] + kw)) * 256 + c0;
      *(int4*)(sA0 + dst) = *(const int4*)(a0cl + ga + cb);
      *(int4*)(sA1 + dst) = *(const int4*)(a1cl + ga + cb);
      size_t gb = (size_t)(n0 + r) * KT + kb * 128;
      *(int4*)(sB + dst) = *(const int4*)(bw + gb + cb);
    }
    __syncthreads();
#pragma unroll
    for (int ks = 0; ks < 2; ++ks) {
      const int kbyte = ks * 64 + ((lane >> 4) << 4);   // 16 i8 per lane
      i32x4 bfr[4], af0[2], af1[2];
#pragma unroll
      for (int r = 0; r < 4; ++r) {
        int rr = wn * 64 + r * 16 + (lane & 15);
        bfr[r] = *(const i32x4*)(sB + rr * 128 + (kbyte ^ ((rr & 7) << 4)));
      }
#pragma unroll
      for (int q = 0; q < 2; ++q) {
        int rr = wm * 32 + q * 16 + (lane & 15);
        int off = rr * 128 + (kbyte ^ ((rr & 7) << 4));
        af0[q] = *(const i32x4*)(sA0 + off);
        af1[q] = *(const i32x4*)(sA1 + off);
      }
#pragma unroll
      for (int q = 0; q < 2; ++q)
#pragma unroll
        for (int r = 0; r < 4; ++r) {
          acc0[q][r] = __builtin_amdgcn_mfma_i32_16x16x64_i8(af0[q], bfr[r], acc0[q][r], 0, 0, 0);
          acc1[q][r] = __builtin_amdgcn_mfma_i32_16x16x64_i8(af1[q], bfr[r], acc1[q][r], 0, 0, 0);
        }
    }
  }

  int mx0 = 0, mx1 = 0;
#pragma unroll
  for (int q = 0; q < 2; ++q)
#pragma unroll
    for (int r = 0; r < 4; ++r) {
      const int mrow0 = m0 + wm * 32 + q * 16 + ((lane >> 4) << 2);
      const int co = n0 + wn * 64 + r * 16 + (lane & 15);
#pragma unroll
      for (int e = 0; e < 4; ++e) {
        int v0 = acc0[q][r][e], v1 = acc1[q][r][e];
        mx0 = max(mx0, v0 < 0 ? -v0 : v0);
        mx1 = max(mx1, v1 < 0 ? -v1 : v1);
        size_t idx = (size_t)(mrow0 + e) * COUTc + co;
        p0[idx] = (short)v0;
        p1[idx] = (short)v1;
      }
    }
#pragma unroll
  for (int off = 32; off; off >>= 1) {
    mx0 = max(mx0, __shfl_xor(mx0, off));
    mx1 = max(mx1, __shfl_xor(mx1, off));
  }
  if (lane == 0) { red[wid] = mx0; red[wid + 8] = mx1; }
  __syncthreads();
  if (tid == 0) {
    int a = 0, b = 0;
#pragma unroll
    for (int i = 0; i < 8; ++i) { a = max(a, red[i]); b = max(b, red[i + 8]); }
    atomicMax(scal + 1, a);
    atomicMax(scal + 2, b);
  }
}

__device__ __forceinline__ float compute_val(int a, int b, float sa0, float sa1) {
  float q0 = rintf(__fdiv_rn((float)a, sa0));
  q0 = fminf(31.f, fmaxf(-31.f, q0));
  float q1 = rintf(__fdiv_rn((float)b, sa1));
  q1 = fminf(31.f, fmaxf(-31.f, q1));
  float acc = __fadd_rn(__fmul_rn(q0, sa0), __fmul_rn(__fmul_rn(q1, sa1), 4.0f));
  float pe = (float)(a + 4 * b);
  return __fadd_rn(pe, __fsub_rn(acc, pe));
}

__global__ __launch_bounds__(256) void k_maxval(const short* __restrict__ p0,
                                                const short* __restrict__ p1,
                                                const int* __restrict__ scal,
                                                unsigned int* scalu) {
  const float sa0 = fmaxf(__fdiv_rn((float)scal[1], 31.0f), 1e-12f);
  const float sa1 = fmaxf(__fdiv_rn((float)scal[2], 31.0f), 1e-12f);
  int i = blockIdx.x * 256 + threadIdx.x;
  const short4 a = ((const short4*)p0)[i];
  const short4 b = ((const short4*)p1)[i];
  float mx = fmaxf(fmaxf(fabsf(compute_val(a.x, b.x, sa0, sa1)),
                         fabsf(compute_val(a.y, b.y, sa0, sa1))),
                   fmaxf(fabsf(compute_val(a.z, b.z, sa0, sa1)),
                         fabsf(compute_val(a.w, b.w, sa0, sa1))));
#pragma unroll
  for (int off = 32; off; off >>= 1) mx = fmaxf(mx, __shfl_xor(mx, off));
  __shared__ float red[4];
  if ((threadIdx.x & 63) == 0) red[threadIdx.x >> 6] = mx;
  __syncthreads();
  if (threadIdx.x == 0) {
    mx = fmaxf(fmaxf(red[0], red[1]), fmaxf(red[2], red[3]));
    atomicMax(scalu + 3, __float_as_uint(mx));
  }
}

__global__ __launch_bounds__(256) void k_final(const short* __restrict__ p0,
                                               const short* __restrict__ p1,
                                               const unsigned int* __restrict__ scalu,
                                               const float* __restrict__ bias,
                                               float* __restrict__ out) {
  __shared__ short t0[64 * 66];
  __shared__ short t1[64 * 66];
  const int* scali = (const int*)scalu;
  const float sx  = fmaxf(__fdiv_rn(__uint_as_float(scalu[0]), 7.0f), 1e-12f);
  const float sa0 = fmaxf(__fdiv_rn((float)scali[1], 31.0f), 1e-12f);
  const float sa1 = fmaxf(__fdiv_rn((float)scali[2], 31.0f), 1e-12f);
  const float so  = fmaxf(__fdiv_rn(__fmul_rn(__uint_as_float(scalu[3]), sx), 127.0f), 1e-12f);

  const int m0 = blockIdx.x * 64, co0 = blockIdx.y * 64;
  const int trow = threadIdx.x >> 3, tseg = threadIdx.x & 7;
#pragma unroll
  for (int p = 0; p < 2; ++p) {
    int ml = p * 32 + trow;
    int4 v0 = *(const int4*)&p0[(size_t)(m0 + ml) * COUTc + co0 + tseg * 8];
    int4 v1 = *(const int4*)&p1[(size_t)(m0 + ml) * COUTc + co0 + tseg * 8];
    const short* s0 = (const short*)&v0;
    const short* s1 = (const short*)&v1;
#pragma unroll
    for (int j = 0; j < 8; ++j) {
      int col = tseg * 8 + j;
      t0[col * 66 + ml] = s0[j];
      t1[col * 66 + ml] = s1[j];
    }
  }
  __syncthreads();
  const int lane16 = threadIdx.x & 15, cg = threadIdx.x >> 4;
#pragma unroll
  for (int p = 0; p < 4; ++p) {
    int col = p * 16 + cg;
    int m4 = lane16 * 4;
    int mg = m0 + m4;
    int nimg = mg / LSP;
    int l = mg - nimg * LSP;
    int co = co0 + col;
    float bv = bias[co];
    float4 o;
    float* op = &o.x;
#pragma unroll
    for (int e = 0; e < 4; ++e) {
      float val = compute_val(t0[col * 66 + m4 + e], t1[col * 66 + m4 + e], sa0, sa1);
      float u = __fmul_rn(val, sx);
      float r = rintf(__fdiv_rn(u, so));
      r = fminf(127.f, fmaxf(-127.f, r));
      op[e] = __fadd_rn(__fmul_rn(r, so), bv);
    }
    *(float4*)&out[((size_t)nimg * COUTc + co) * LSP + l] = o;
  }
}

extern "C" void kernel_launch(void* const* d_in, const int* in_sizes, int n_in,
                              void* d_out, int out_size, void* d_ws, size_t ws_size,
                              hipStream_t stream) {
  const float* x    = (const float*)d_in[0];
  const float* w    = (const float*)d_in[1];
  const float* bias = (const float*)d_in[2];
  float* out = (float*)d_out;
  char* ws = (char*)d_ws;

  unsigned int* scalu = (unsigned int*)ws;
  int* scali = (int*)ws;
  char* a0 = ws + OFF_A0;
  char* a1 = ws + OFF_A1;
  char* bw = ws + OFF_BW;
  short* p0 = (short*)(ws + OFF_P0);
  short* p1 = (short*)(ws + OFF_P1);

  hipMemsetAsync(ws, 0, 64, stream);
  hipMemsetAsync(ws + OFF_A0, 0, 2 * SZ_ACL, stream);   // zero padding borders

  k_absmax<<<1024, 256, 0, stream>>>(x, scalu, NB * CINc * Hc * Wc / 4);
  k_binw<<<COUTc, 256, 0, stream>>>(w, bw);
  k_quant<<<NB * Hc, 1024, 0, stream>>>(x, scalu, a0, a1);
  k_gemm<<<(MD / 128) * (COUTc / 128), 512, 0, stream>>>(a0, a1, bw, p0, p1, scali);
  k_maxval<<<(MD * COUTc) / (4 * 256), 256, 0, stream>>>(p0, p1, scali, scalu);
  k_final<<<dim3(MD / 64, COUTc / 64), 256, 0, stream>>>(p0, p1, scalu, bias, out);
}

// Round 5
// 117.410 us; speedup vs baseline: 1.4933x; 1.0145x over previous
//
#include <hip/hip_runtime.h>
#include <hip/hip_bf16.h>

typedef int i32x4 __attribute__((ext_vector_type(4)));

namespace {
constexpr int NB = 4, CINc = 256, Hc = 56, Wc = 56, COUTc = 256;
constexpr int LSP = 56 * 56;           // 3136 output pixels per image
constexpr int MD  = NB * LSP;          // 12544 GEMM rows
constexpr int KT  = 2304;              // 256*9
constexpr int YP = 58, XP = 58;        // padded spatial

// workspace (i8 activations/weights)
constexpr size_t OFF_A0 = 256;
constexpr size_t SZ_ACL = (size_t)NB * YP * XP * 256;       // 3,444,736 (i8)
constexpr size_t OFF_A1 = OFF_A0 + SZ_ACL;
constexpr size_t OFF_BW = OFF_A1 + SZ_ACL;                  // 6,889,728 (16-aligned)
constexpr size_t SZ_BW  = (size_t)COUTc * KT;               // 589,824 (i8)
constexpr size_t OFF_P0 = OFF_BW + SZ_BW;
constexpr size_t SZ_P   = (size_t)MD * COUTc * 2;           // 6,422,528 (i16)
constexpr size_t OFF_P1 = OFF_P0 + SZ_P;                    // total ~20.3 MB

constexpr int kZeroSlots = (int)((OFF_A0 + 2 * SZ_ACL) / 16);   // 430,608 int4 slots
} // namespace

// zero scalars + a0/a1 (incl. pad borders). Replaces the 40 µs rocclr fill.
__global__ __launch_bounds__(256) void k_zero(int4* __restrict__ p, int n) {
  int i = blockIdx.x * 256 + threadIdx.x;
  if (i < n) p[i] = int4{0, 0, 0, 0};
}

__global__ __launch_bounds__(256) void k_absmax(const float* __restrict__ x,
                                                unsigned int* scal, int n4) {
  float mx = 0.f;
  const float4* x4 = (const float4*)x;
  for (int i = blockIdx.x * blockDim.x + threadIdx.x; i < n4; i += gridDim.x * blockDim.x) {
    float4 v = x4[i];
    mx = fmaxf(mx, fmaxf(fmaxf(fabsf(v.x), fabsf(v.y)), fmaxf(fabsf(v.z), fabsf(v.w))));
  }
#pragma unroll
  for (int off = 32; off; off >>= 1) mx = fmaxf(mx, __shfl_xor(mx, off));
  __shared__ float red[4];
  if ((threadIdx.x & 63) == 0) red[threadIdx.x >> 6] = mx;
  __syncthreads();
  if (threadIdx.x == 0) {
    mx = fmaxf(fmaxf(red[0], red[1]), fmaxf(red[2], red[3]));
    atomicMax(scal, __float_as_uint(mx));
  }
}

// quantize x -> i8 DAC slices, NCHW -> padded channels-last [n][y][x][c]
__global__ __launch_bounds__(1024) void k_quant(const float* __restrict__ x,
                                                const unsigned int* __restrict__ scal,
                                                char* __restrict__ a0,
                                                char* __restrict__ a1) {
  __shared__ char t0[56 * 256];
  __shared__ char t1[56 * 256];
  const int n = blockIdx.x / Hc, h = blockIdx.x % Hc;
  const float sx = fmaxf(__fdiv_rn(__uint_as_float(scal[0]), 7.0f), 1e-12f);
  const int c = threadIdx.x & 255, wq = threadIdx.x >> 8;
  const float2* src = (const float2*)(x + (((size_t)n * CINc + c) * Hc + h) * Wc + wq * 14);
#pragma unroll
  for (int j = 0; j < 7; ++j) {
    float2 v = src[j];
    float arr[2] = {v.x, v.y};
#pragma unroll
    for (int e = 0; e < 2; ++e) {
      float qf = rintf(__fdiv_rn(arr[e], sx));
      qf = fminf(7.f, fmaxf(-7.f, qf));
      int qi = (int)qf;
      int mag = qi < 0 ? -qi : qi;
      int s0 = mag & 3, s1 = mag >> 2;
      if (qi < 0) { s0 = -s0; s1 = -s1; }
      int w = wq * 14 + j * 2 + e;
      t0[w * 256 + c] = (char)s0;
      t1[w * 256 + c] = (char)s1;
    }
  }
  __syncthreads();
  {
    int idx = threadIdx.x;              // 56*16 = 896 int4 slots per array
    if (idx < 896) {
      int wr = idx >> 4, c16 = (idx & 15) << 4;
      int4 v0 = *(const int4*)&t0[wr * 256 + c16];
      int4 v1 = *(const int4*)&t1[wr * 256 + c16];
      size_t dst = (((size_t)n * YP + (h + 1)) * XP + (wr + 1)) * 256 + c16;
      *(int4*)&a0[dst] = v0;
      *(int4*)&a1[dst] = v1;
    }
  }
}

// binarize weights -> i8 {+1,-1}, reorder to [co][k'], k' = (kh*3+kw)*256 + cin
// coalesced reads (thread-consecutive floats) -> LDS -> coalesced char4 writes
__global__ __launch_bounds__(256) void k_binw(const float* __restrict__ w,
                                              char* __restrict__ bw) {
  __shared__ char s[KT];
  const int co = blockIdx.x;
  const float* src = w + (size_t)co * KT;
#pragma unroll
  for (int t = threadIdx.x; t < KT; t += 256)         // t = cin*9 + s_idx
    s[t] = src[t] >= 0.f ? (char)1 : (char)-1;
  __syncthreads();
  char4* dst = (char4*)(bw + (size_t)co * KT);
#pragma unroll
  for (int j4 = threadIdx.x; j4 < KT / 4; j4 += 256) {
    char4 v;
    char* vp = (char*)&v;
#pragma unroll
    for (int e = 0; e < 4; ++e) {
      int j = j4 * 4 + e;                             // j = s_idx*256 + cin
      int s_idx = j >> 8, cin = j & 255;
      vp[e] = s[cin * 9 + s_idx];
    }
    dst[j4] = v;
  }
}

// 128x128 tile, 8 waves (4m x 2n, each 32x64), i8 MFMA, dual accumulator.
__global__ __launch_bounds__(512) void k_gemm(const char* __restrict__ a0cl,
                                              const char* __restrict__ a1cl,
                                              const char* __restrict__ bw,
                                              short* __restrict__ p0, short* __restrict__ p1,
                                              int* scal) {
  __shared__ __align__(16) char sA0[128 * 128];
  __shared__ __align__(16) char sA1[128 * 128];
  __shared__ __align__(16) char sB[128 * 128];
  __shared__ int red[16];

  const int tid = threadIdx.x;
  const int lane = tid & 63, wid = tid >> 6;
  const int wm = wid >> 1, wn = wid & 1;          // 4x2 waves, 32x64 each

  // bijective XCD swizzle for 196 blocks (196 = 8*24 + 4), n-fastest within chunk
  const int bid = blockIdx.x;
  const int xcd = bid & 7;
  const int wg = (xcd < 4 ? xcd * 25 : 100 + (xcd - 4) * 24) + (bid >> 3);
  const int nblk = wg & 1, mblk = wg >> 1;
  const int m0 = mblk * 128, n0 = nblk * 128;

  i32x4 acc0[2][4] = {};
  i32x4 acc1[2][4] = {};

  const int trow = tid >> 3;          // 0..63
  const int cb = (tid & 7) * 16;      // 16B seg within 128B row

  int rn[2], roh[2], rww[2];
#pragma unroll
  for (int p = 0; p < 2; ++p) {
    int m = m0 + p * 64 + trow;
    rn[p] = m / LSP; int l = m - rn[p] * LSP;
    roh[p] = l / 56; rww[p] = l - roh[p] * 56;
  }

#pragma unroll 1
  for (int kb = 0; kb < KT / 128; ++kb) {         // 18 iters, K-step = 128 i8
    const int slab = kb >> 1;                     // (kh,kw) 0..8
    const int kh = slab / 3, kw = slab - (slab / 3) * 3;
    const int c0 = (kb & 1) << 7;
    __syncthreads();
#pragma unroll
    for (int p = 0; p < 2; ++p) {
      const int r = p * 64 + trow;
      const int dst = r * 128 + (cb ^ ((r & 7) << 4));
      size_t ga = (((size_t)rn[p] * YP + (roh[p] + kh)) * XP + (rww[p] + kw)) * 256 + c0;
      *(int4*)(sA0 + dst) = *(const int4*)(a0cl + ga + cb);
      *(int4*)(sA1 + dst) = *(const int4*)(a1cl + ga + cb);
      size_t gb = (size_t)(n0 + r) * KT + kb * 128;
      *(int4*)(sB + dst) = *(const int4*)(bw + gb + cb);
    }
    __syncthreads();
#pragma unroll
    for (int ks = 0; ks < 2; ++ks) {
      const int kbyte = ks * 64 + ((lane >> 4) << 4);   // 16 i8 per lane
      i32x4 bfr[4], af0[2], af1[2];
#pragma unroll
      for (int r = 0; r < 4; ++r) {
        int rr = wn * 64 + r * 16 + (lane & 15);
        bfr[r] = *(const i32x4*)(sB + rr * 128 + (kbyte ^ ((rr & 7) << 4)));
      }
#pragma unroll
      for (int q = 0; q < 2; ++q) {
        int rr = wm * 32 + q * 16 + (lane & 15);
        int off = rr * 128 + (kbyte ^ ((rr & 7) << 4));
        af0[q] = *(const i32x4*)(sA0 + off);
        af1[q] = *(const i32x4*)(sA1 + off);
      }
#pragma unroll
      for (int q = 0; q < 2; ++q)
#pragma unroll
        for (int r = 0; r < 4; ++r) {
          acc0[q][r] = __builtin_amdgcn_mfma_i32_16x16x64_i8(af0[q], bfr[r], acc0[q][r], 0, 0, 0);
          acc1[q][r] = __builtin_amdgcn_mfma_i32_16x16x64_i8(af1[q], bfr[r], acc1[q][r], 0, 0, 0);
        }
    }
  }

  int mx0 = 0, mx1 = 0;
#pragma unroll
  for (int q = 0; q < 2; ++q)
#pragma unroll
    for (int r = 0; r < 4; ++r) {
      const int mrow0 = m0 + wm * 32 + q * 16 + ((lane >> 4) << 2);
      const int co = n0 + wn * 64 + r * 16 + (lane & 15);
#pragma unroll
      for (int e = 0; e < 4; ++e) {
        int v0 = acc0[q][r][e], v1 = acc1[q][r][e];
        mx0 = max(mx0, v0 < 0 ? -v0 : v0);
        mx1 = max(mx1, v1 < 0 ? -v1 : v1);
        size_t idx = (size_t)(mrow0 + e) * COUTc + co;
        p0[idx] = (short)v0;
        p1[idx] = (short)v1;
      }
    }
#pragma unroll
  for (int off = 32; off; off >>= 1) {
    mx0 = max(mx0, __shfl_xor(mx0, off));
    mx1 = max(mx1, __shfl_xor(mx1, off));
  }
  if (lane == 0) { red[wid] = mx0; red[wid + 8] = mx1; }
  __syncthreads();
  if (tid == 0) {
    int a = 0, b = 0;
#pragma unroll
    for (int i = 0; i < 8; ++i) { a = max(a, red[i]); b = max(b, red[i + 8]); }
    atomicMax(scal + 1, a);
    atomicMax(scal + 2, b);
  }
}

__device__ __forceinline__ float compute_val(int a, int b, float sa0, float sa1) {
  float q0 = rintf(__fdiv_rn((float)a, sa0));
  q0 = fminf(31.f, fmaxf(-31.f, q0));
  float q1 = rintf(__fdiv_rn((float)b, sa1));
  q1 = fminf(31.f, fmaxf(-31.f, q1));
  float acc = __fadd_rn(__fmul_rn(q0, sa0), __fmul_rn(__fmul_rn(q1, sa1), 4.0f));
  float pe = (float)(a + 4 * b);
  return __fadd_rn(pe, __fsub_rn(acc, pe));
}

__global__ __launch_bounds__(256) void k_maxval(const short* __restrict__ p0,
                                                const short* __restrict__ p1,
                                                const int* __restrict__ scal,
                                                unsigned int* scalu) {
  const float sa0 = fmaxf(__fdiv_rn((float)scal[1], 31.0f), 1e-12f);
  const float sa1 = fmaxf(__fdiv_rn((float)scal[2], 31.0f), 1e-12f);
  int i = blockIdx.x * 256 + threadIdx.x;
  const short4 a = ((const short4*)p0)[i];
  const short4 b = ((const short4*)p1)[i];
  float mx = fmaxf(fmaxf(fabsf(compute_val(a.x, b.x, sa0, sa1)),
                         fabsf(compute_val(a.y, b.y, sa0, sa1))),
                   fmaxf(fabsf(compute_val(a.z, b.z, sa0, sa1)),
                         fabsf(compute_val(a.w, b.w, sa0, sa1))));
#pragma unroll
  for (int off = 32; off; off >>= 1) mx = fmaxf(mx, __shfl_xor(mx, off));
  __shared__ float red[4];
  if ((threadIdx.x & 63) == 0) red[threadIdx.x >> 6] = mx;
  __syncthreads();
  if (threadIdx.x == 0) {
    mx = fmaxf(fmaxf(red[0], red[1]), fmaxf(red[2], red[3]));
    atomicMax(scalu + 3, __float_as_uint(mx));
  }
}

__global__ __launch_bounds__(256) void k_final(const short* __restrict__ p0,
                                               const short* __restrict__ p1,
                                               const unsigned int* __restrict__ scalu,
                                               const float* __restrict__ bias,
                                               float* __restrict__ out) {
  __shared__ short t0[64 * 66];
  __shared__ short t1[64 * 66];
  const int* scali = (const int*)scalu;
  const float sx  = fmaxf(__fdiv_rn(__uint_as_float(scalu[0]), 7.0f), 1e-12f);
  const float sa0 = fmaxf(__fdiv_rn((float)scali[1], 31.0f), 1e-12f);
  const float sa1 = fmaxf(__fdiv_rn((float)scali[2], 31.0f), 1e-12f);
  const float so  = fmaxf(__fdiv_rn(__fmul_rn(__uint_as_float(scalu[3]), sx), 127.0f), 1e-12f);

  const int m0 = blockIdx.x * 64, co0 = blockIdx.y * 64;
  const int trow = threadIdx.x >> 3, tseg = threadIdx.x & 7;
#pragma unroll
  for (int p = 0; p < 2; ++p) {
    int ml = p * 32 + trow;
    int4 v0 = *(const int4*)&p0[(size_t)(m0 + ml) * COUTc + co0 + tseg * 8];
    int4 v1 = *(const int4*)&p1[(size_t)(m0 + ml) * COUTc + co0 + tseg * 8];
    const short* s0 = (const short*)&v0;
    const short* s1 = (const short*)&v1;
#pragma unroll
    for (int j = 0; j < 8; ++j) {
      int col = tseg * 8 + j;
      t0[col * 66 + ml] = s0[j];
      t1[col * 66 + ml] = s1[j];
    }
  }
  __syncthreads();
  const int lane16 = threadIdx.x & 15, cg = threadIdx.x >> 4;
#pragma unroll
  for (int p = 0; p < 4; ++p) {
    int col = p * 16 + cg;
    int m4 = lane16 * 4;
    int mg = m0 + m4;
    int nimg = mg / LSP;
    int l = mg - nimg * LSP;
    int co = co0 + col;
    float bv = bias[co];
    float4 o;
    float* op = &o.x;
#pragma unroll
    for (int e = 0; e < 4; ++e) {
      float val = compute_val(t0[col * 66 + m4 + e], t1[col * 66 + m4 + e], sa0, sa1);
      float u = __fmul_rn(val, sx);
      float r = rintf(__fdiv_rn(u, so));
      r = fminf(127.f, fmaxf(-127.f, r));
      op[e] = __fadd_rn(__fmul_rn(r, so), bv);
    }
    *(float4*)&out[((size_t)nimg * COUTc + co) * LSP + l] = o;
  }
}

extern "C" void kernel_launch(void* const* d_in, const int* in_sizes, int n_in,
                              void* d_out, int out_size, void* d_ws, size_t ws_size,
                              hipStream_t stream) {
  const float* x    = (const float*)d_in[0];
  const float* w    = (const float*)d_in[1];
  const float* bias = (const float*)d_in[2];
  float* out = (float*)d_out;
  char* ws = (char*)d_ws;

  unsigned int* scalu = (unsigned int*)ws;
  int* scali = (int*)ws;
  char* a0 = ws + OFF_A0;
  char* a1 = ws + OFF_A1;
  char* bw = ws + OFF_BW;
  short* p0 = (short*)(ws + OFF_P0);
  short* p1 = (short*)(ws + OFF_P1);

  k_zero<<<(kZeroSlots + 255) / 256, 256, 0, stream>>>((int4*)ws, kZeroSlots);
  k_absmax<<<1024, 256, 0, stream>>>(x, scalu, NB * CINc * Hc * Wc / 4);
  k_binw<<<COUTc, 256, 0, stream>>>(w, bw);
  k_quant<<<NB * Hc, 1024, 0, stream>>>(x, scalu, a0, a1);
  k_gemm<<<(MD / 128) * (COUTc / 128), 512, 0, stream>>>(a0, a1, bw, p0, p1, scali);
  k_maxval<<<(MD * COUTc) / (4 * 256), 256, 0, stream>>>(p0, p1, scali, scalu);
  k_final<<<dim3(MD / 64, COUTc / 64), 256, 0, stream>>>(p0, p1, scalu, bias, out);
}